// Round 1
// 1087.910 us; speedup vs baseline: 1.2016x; 1.2016x over previous
//
#include <hip/hip_runtime.h>
#include <stdint.h>
#include <math.h>

typedef unsigned short u16;
typedef __attribute__((ext_vector_type(8))) short bf16x8;   // 8 bf16 (4 VGPRs)
typedef __attribute__((ext_vector_type(4))) float f32x4;    // MFMA accumulator

#define HS   1024
#define NEXP 8
#define FFN  4096

// ---------- small helpers ----------
__device__ __forceinline__ u16 f2b(float f) {              // fp32 -> bf16, RNE
  uint32_t u = __builtin_bit_cast(uint32_t, f);
  u = (u + 0x7fffu + ((u >> 16) & 1u)) >> 16;
  return (u16)u;
}
__device__ __forceinline__ float gelu_tanh(float x) {      // JAX approximate=True
  float z = 0.7978845608028654f * (x + 0.044715f * x * x * x);
  float e = __expf(2.0f * z);
  return 0.5f * x * (1.0f + (1.0f - 2.0f / (e + 1.0f)));
}
__device__ __forceinline__ void gload_lds16(const void* g, void* l) {
  // async global->LDS, 16B/lane; global addr per-lane, LDS dst wave-uniform+lane*16
  __builtin_amdgcn_global_load_lds(
      (__attribute__((address_space(1))) void*)(void*)g,
      (__attribute__((address_space(3))) void*)l, 16, 0, 0);
}

// ---------- x: fp32 -> bf16, token order (fallback path only) ----------
__global__ __launch_bounds__(256) void convert_bf16(const float* __restrict__ in,
                                                    u16* __restrict__ out) {
  const int i = (blockIdx.x * 256 + threadIdx.x) * 4;
  float4 v = *(const float4*)(in + i);
  ushort4 o;
  o.x = f2b(v.x); o.y = f2b(v.y); o.z = f2b(v.z); o.w = f2b(v.w);
  *(ushort4*)(out + i) = o;
}

// ---------- transpose + convert (batched over z):  [z][K][N] f32 -> [z][N][K] bf16 ----------
__global__ __launch_bounds__(256) void transpose_convert(const float* __restrict__ in,
                                                         u16* __restrict__ out,
                                                         int K, int N) {
  __shared__ u16 tile[32][33];
  const int z = blockIdx.z;
  const int k0 = blockIdx.y * 32, n0 = blockIdx.x * 32;
  const int tx = threadIdx.x & 31, ty = threadIdx.x >> 5;   // 32 x 8
  const float* src = in + (size_t)z * K * N;
  u16* dst = out + (size_t)z * N * K;
#pragma unroll
  for (int i = 0; i < 4; ++i)
    tile[ty + i * 8][tx] = f2b(src[(size_t)(k0 + ty + i * 8) * N + n0 + tx]);
  __syncthreads();
#pragma unroll
  for (int i = 0; i < 4; ++i)
    dst[(size_t)(n0 + ty + i * 8) * K + k0 + tx] = tile[tx][ty + i * 8];
}

// ---------- router: fp64 logits, softmax, top-2 (tie -> lower index) ----------
__global__ __launch_bounds__(256) void router_kernel(const float* __restrict__ x,
                                                     const float* __restrict__ wr,
                                                     int T, int* __restrict__ experts,
                                                     float* __restrict__ weights) {
  const int wave = threadIdx.x >> 6, lane = threadIdx.x & 63;
  const int t = blockIdx.x * 4 + wave;
  if (t >= T) return;
  const float* xr = x + (size_t)t * HS;
  double acc[8] = {0, 0, 0, 0, 0, 0, 0, 0};
#pragma unroll
  for (int i = 0; i < HS / 64; ++i) {
    const int hrow = i * 64 + lane;
    double xv = (double)xr[hrow];
    float4 w0 = *(const float4*)(wr + hrow * 8);
    float4 w1 = *(const float4*)(wr + hrow * 8 + 4);
    acc[0] += xv * (double)w0.x; acc[1] += xv * (double)w0.y;
    acc[2] += xv * (double)w0.z; acc[3] += xv * (double)w0.w;
    acc[4] += xv * (double)w1.x; acc[5] += xv * (double)w1.y;
    acc[6] += xv * (double)w1.z; acc[7] += xv * (double)w1.w;
  }
#pragma unroll
  for (int e = 0; e < 8; ++e) {
    double v = acc[e];
#pragma unroll
    for (int off = 32; off > 0; off >>= 1) v += __shfl_xor(v, off, 64);
    acc[e] = v;
  }
  if (lane == 0) {
    double m = acc[0];
#pragma unroll
    for (int e = 1; e < 8; ++e) m = acc[e] > m ? acc[e] : m;
    double s[8], sum = 0.0;
#pragma unroll
    for (int e = 0; e < 8; ++e) { s[e] = exp(acc[e] - m); sum += s[e]; }
    double inv = 1.0 / sum;
    int e1 = 0; double l1 = acc[0];
#pragma unroll
    for (int e = 1; e < 8; ++e) if (acc[e] > l1) { l1 = acc[e]; e1 = e; }
    int e2 = -1; double l2 = -1e300;
#pragma unroll
    for (int e = 0; e < 8; ++e) if (e != e1 && acc[e] > l2) { l2 = acc[e]; e2 = e; }
    experts[2 * t] = e1;  experts[2 * t + 1] = e2;
    weights[2 * t] = (float)(s[e1] * inv);
    weights[2 * t + 1] = (float)(s[e2] * inv);
  }
}

// ---------- per-wave expert histogram + in-wave stable rank ----------
__global__ __launch_bounds__(256) void hist_kernel(const int* __restrict__ experts,
                                                   int* __restrict__ hist,
                                                   unsigned char* __restrict__ lrank) {
  const int n = blockIdx.x * 256 + threadIdx.x;
  const int lane = threadIdx.x & 63;
  const int wid = n >> 6;
  const int e = experts[n];
  int rank = 0;
#pragma unroll
  for (int ev = 0; ev < 8; ++ev) {
    unsigned long long m = __ballot(e == ev);
    if (lane == ev) hist[wid * 8 + ev] = __popcll(m);
    if (e == ev) rank = __popcll(m & ((1ull << lane) - 1ull));
  }
  lrank[n] = (unsigned char)rank;
}

// ---------- single-block scan: chunk-EXCLUSIVE prefix per expert ----------
__global__ __launch_bounds__(512) void scan_kernel(const int* __restrict__ hist,
                                                   int* __restrict__ chunkBase) {
  __shared__ int s[512];
  const int tid = threadIdx.x;     // 512 == nChunks
  for (int e = 0; e < 8; ++e) {
    int v = hist[tid * 8 + e];
    s[tid] = v;
    __syncthreads();
    for (int off = 1; off < 512; off <<= 1) {
      int add = (tid >= off) ? s[tid - off] : 0;
      __syncthreads();
      s[tid] += add;
      __syncthreads();
    }
    chunkBase[tid * 8 + e] = s[tid] - v;   // exclusive, within-expert offset
    __syncthreads();
  }
}

// ---------- slot map init ----------
__global__ __launch_bounds__(256) void slot_init(int* __restrict__ rowtok,
                                                 float* __restrict__ roww) {
  const int i = blockIdx.x * 256 + threadIdx.x;
  rowtok[i] = -1;
  roww[i] = 0.0f;
}

// ---------- gather: fill rowtok/roww; optionally write xb[slot] = bf16(x[token]) ----------
__global__ __launch_bounds__(256) void gather_kernel(const float* __restrict__ x,
                                                     const int* __restrict__ experts,
                                                     const unsigned char* __restrict__ lrank,
                                                     const int* __restrict__ chunkBase,
                                                     const float* __restrict__ weights,
                                                     int capacity, int* __restrict__ rowtok,
                                                     float* __restrict__ roww,
                                                     u16* __restrict__ xb) {
  const int wave = threadIdx.x >> 6, lane = threadIdx.x & 63;
  const int n = blockIdx.x * 4 + wave;           // one wave per assignment
  const int e = experts[n];
  const int off = chunkBase[(n >> 6) * 8 + e] + (int)lrank[n];
  if (off >= capacity) return;
  const int slot = e * capacity + off;
  if (lane == 0) { rowtok[slot] = n >> 1; roww[slot] = weights[n]; }
  if (xb == nullptr) return;
  const float* src = x + (size_t)(n >> 1) * HS;
  u16* dst = xb + (size_t)slot * HS;
#pragma unroll
  for (int i = 0; i < 4; ++i) {
    float4 v = *(const float4*)(src + i * 256 + lane * 4);
    ushort4 o;
    o.x = f2b(v.x); o.y = f2b(v.y); o.z = f2b(v.z); o.w = f2b(v.w);
    *(ushort4*)(dst + i * 256 + lane * 4) = o;
  }
}

// ---------- bias broadcast into out ----------
__global__ __launch_bounds__(256) void bias_init(const float* __restrict__ bias,
                                                 float* __restrict__ out) {
  const int c = threadIdx.x * 4;
  *(float4*)(out + (size_t)blockIdx.x * HS + c) = *(const float4*)(bias + c);
}

// ============================================================================
// 256x256 / BK=64 / 8-wave / 8-phase GEMM (T2 swizzle + T3/T4 counted vmcnt +
// T5 setprio).  A [z][M][K] (or gathered rows), Bt [z][Nn][K], bf16.
// SCATTER: atomically adds roww*acc into out[rowtok[row]]; else bf16 (GELU) C.
// Schedule (per iter, tiles T0=2I buf0 / T1=2I+1 buf1, 1 half-tile stage/phase):
//   p0: B(T1)h0->B1   p1: B(T1)h1   p2: A(T0+2)h0->A0   p3: A(T0+2)h1, vmcnt(4)
//   p4: B(T0+2)h0->B0 p5: B(T0+2)h1 p6: A(T1+2)h0->A1   p7: A(T1+2)h1, vmcnt(4)
// Each LDS region is staged strictly after the barrier closing its last-read
// phase (A-frags read only at group-head phase; B-frag nf read at phase nf).
// vmcnt(4) @p3 completes {A(T1),B(T1)}; @p7 completes {A(T0+2),B(T0+2)}.
// LDS swizzle: slot byte b holds element (b ^ ((row&7)<<4)), row=b>>7 —
// realized by inverse-swizzling the global SOURCE (linear gload_lds dest).
// ============================================================================
#define VMCNT(n) asm volatile("s_waitcnt vmcnt(" #n ")" ::: "memory")
#define BAR() do { asm volatile("" ::: "memory"); \
                   __builtin_amdgcn_s_barrier();  \
                   asm volatile("" ::: "memory"); } while (0)

template <bool GELU, bool GATHER_A, bool SCATTER>
__global__ __launch_bounds__(512, 2) void gemm_moe(const u16* __restrict__ A,
                                                   const u16* __restrict__ Bt,
                                                   u16* __restrict__ Cout,
                                                   float* __restrict__ out,
                                                   const int* __restrict__ rowtok,
                                                   const float* __restrict__ roww,
                                                   int rtStride, int M, int Nn, int K) {
  const int z = blockIdx.z;
  const int bm = blockIdx.y, bn = blockIdx.x;
  if (!GATHER_A) A += (size_t)z * M * K;
  Bt += (size_t)z * Nn * K;
  rowtok += (size_t)z * rtStride;
  roww += (size_t)z * rtStride;
  const u16* Bb = Bt + (size_t)bn * 256 * K;

  __shared__ u16 lds[65536];          // 128 KiB: A0 A1 B0 B1, 32 KiB each
  char* ldsA = (char*)lds;
  char* ldsB = ldsA + 65536;

  const int tid = threadIdx.x;
  const int lane = tid & 63;
  const int lrow = lane & 15, quad = lane >> 4;
  const int wid = tid >> 6, wm = wid >> 2, wn = wid & 3;  // 2x4 waves -> 128x64 each

  // swizzled read offsets: byte = row*128 + ((ks*64 + quad*16) ^ ((row&7)<<4))
  const int swz = (lane & 7) << 4;                        // row&7 == lane&7
  const int kq0 = (quad * 16) ^ swz;
  const int kq1 = (64 + quad * 16) ^ swz;
  const int aBase = (wm * 128 + lrow) * 128;
  const int bBase = (wn * 64 + lrow) * 128;

  // staging sources: 4 row-steps of 64 rows; source col inverse-swizzled
  const u16 *gA[4], *gB[4];
#pragma unroll
  for (int s = 0; s < 4; ++s) {
    const int srow = s * 64 + (tid >> 3);
    const int scol = ((tid & 7) * 8) ^ ((srow & 7) << 3);   // elements
    if (GATHER_A) {
      int t = rowtok[bm * 256 + srow]; if (t < 0) t = 0;
      gA[s] = A + (size_t)t * K + scol;
    } else {
      gA[s] = A + (size_t)(bm * 256 + srow) * K + scol;
    }
    gB[s] = Bb + (size_t)srow * K + scol;
  }
  const int ldst0 = tid * 16;   // linear byte within step (gload dest)

#define STAGE_A(buf, half, kt) do { \
    gload_lds16(gA[(half)*2]   + (size_t)(kt) * 64, ldsA + (buf)*32768 + (half)*16384 +        ldst0); \
    gload_lds16(gA[(half)*2+1] + (size_t)(kt) * 64, ldsA + (buf)*32768 + (half)*16384 + 8192 + ldst0); \
  } while (0)
#define STAGE_B(buf, half, kt) do { \
    gload_lds16(gB[(half)*2]   + (size_t)(kt) * 64, ldsB + (buf)*32768 + (half)*16384 +        ldst0); \
    gload_lds16(gB[(half)*2+1] + (size_t)(kt) * 64, ldsB + (buf)*32768 + (half)*16384 + 8192 + ldst0); \
  } while (0)

  f32x4 acc[8][4] = {};
  bf16x8 a[8][2];

#define LOAD_A(ABUF) \
  _Pragma("unroll") \
  for (int m = 0; m < 8; ++m) { \
    a[m][0] = *(const bf16x8*)((ABUF) + aBase + m * 2048 + kq0); \
    a[m][1] = *(const bf16x8*)((ABUF) + aBase + m * 2048 + kq1); \
  }

#define PHASE(BBUF, NF, STAGE_STMT, TAIL_STMT) do { \
    bf16x8 b0 = *(const bf16x8*)((BBUF) + bBase + (NF) * 2048 + kq0); \
    bf16x8 b1 = *(const bf16x8*)((BBUF) + bBase + (NF) * 2048 + kq1); \
    STAGE_STMT; \
    BAR(); \
    __builtin_amdgcn_s_setprio(1); \
    _Pragma("unroll") \
    for (int m = 0; m < 8; ++m) { \
      acc[m][NF] = __builtin_amdgcn_mfma_f32_16x16x32_bf16(a[m][0], b0, acc[m][NF], 0, 0, 0); \
      acc[m][NF] = __builtin_amdgcn_mfma_f32_16x16x32_bf16(a[m][1], b1, acc[m][NF], 0, 0, 0); \
    } \
    __builtin_amdgcn_s_setprio(0); \
    TAIL_STMT; \
    BAR(); \
  } while (0)

  // prologue: A(0)->A0, B(0)->B0, A(1)->A1 ; wait A(0),B(0) (A(1) stays in flight)
  STAGE_A(0, 0, 0); STAGE_A(0, 1, 0);
  STAGE_B(0, 0, 0); STAGE_B(0, 1, 0);
  STAGE_A(1, 0, 1); STAGE_A(1, 1, 1);
  VMCNT(4);
  BAR();

  const int nIter = K >> 7;            // K/128, >=1; K multiple of 128
  for (int I = 0; I < nIter; ++I) {
    const int T1 = 2 * I + 1;
    const bool hn = (I + 1 < nIter);
    // ---- tile 2I from buf0 ----
    LOAD_A(ldsA);
    PHASE(ldsB, 0, STAGE_B(1, 0, T1), ((void)0));
    PHASE(ldsB, 1, STAGE_B(1, 1, T1), ((void)0));
    PHASE(ldsB, 2, do { if (hn) STAGE_A(0, 0, T1 + 1); } while (0), ((void)0));
    PHASE(ldsB, 3, do { if (hn) STAGE_A(0, 1, T1 + 1); } while (0),
          do { if (hn) { VMCNT(4); } else { VMCNT(0); } } while (0));
    // ---- tile 2I+1 from buf1 ----
    LOAD_A(ldsA + 32768);
    PHASE(ldsB + 32768, 0, do { if (hn) STAGE_B(0, 0, T1 + 1); } while (0), ((void)0));
    PHASE(ldsB + 32768, 1, do { if (hn) STAGE_B(0, 1, T1 + 1); } while (0), ((void)0));
    PHASE(ldsB + 32768, 2, do { if (hn) STAGE_A(1, 0, T1 + 2); } while (0), ((void)0));
    PHASE(ldsB + 32768, 3, do { if (hn) STAGE_A(1, 1, T1 + 2); } while (0),
          do { if (hn) { VMCNT(4); } } while (0));
  }

  // epilogue — C/D layout: col=lane&15, row=quad*4+reg (m89-verified)
  const int rbase = bm * 256 + wm * 128 + quad * 4;
  const int cbase = bn * 256 + wn * 64 + lrow;
  if (!SCATTER) {
    u16* Cb = Cout + (size_t)z * M * Nn;
#pragma unroll
    for (int m = 0; m < 8; ++m)
#pragma unroll
      for (int nf = 0; nf < 4; ++nf)
#pragma unroll
        for (int r = 0; r < 4; ++r) {
          float v = acc[m][nf][r];
          if (GELU) v = gelu_tanh(v);
          Cb[(size_t)(rbase + m * 16 + r) * Nn + cbase + nf * 16] = f2b(v);
        }
  } else {
#pragma unroll
    for (int m = 0; m < 8; ++m)
#pragma unroll
      for (int r = 0; r < 4; ++r) {
        const int row = rbase + m * 16 + r;
        const int tok = rowtok[row];
        if (tok >= 0) {
          const float w = roww[row];
          float* op = out + (size_t)tok * HS + cbase;
#pragma unroll
          for (int nf = 0; nf < 4; ++nf)
            atomicAdd(op + nf * 16, w * acc[m][nf][r]);
        }
      }
  }
}

extern "C" void kernel_launch(void* const* d_in, const int* in_sizes, int n_in,
                              void* d_out, int out_size, void* d_ws, size_t ws_size,
                              hipStream_t stream) {
  const float* x    = (const float*)d_in[0];
  const float* wr   = (const float*)d_in[1];
  const float* w1   = (const float*)d_in[2];
  const float* w2   = (const float*)d_in[3];
  const float* bias = (const float*)d_in[4];
  float* out = (float*)d_out;

  const int T = in_sizes[0] / HS;          // 16384
  const int N = T * 2;                     // 32768 assignments
  const int capacity = N / NEXP;           // 4096
  const int nChunks = N / 64;              // 512

  // ---- small workspace ----
  char* ws = (char*)d_ws;
  int* experts = (int*)ws;                   ws += (size_t)N * 4;
  float* weights = (float*)ws;               ws += (size_t)N * 4;
  unsigned char* lrank = (unsigned char*)ws; ws += (size_t)N;
  int* hist = (int*)ws;                      ws += (size_t)nChunks * 8 * 4;
  int* chunkBase = (int*)ws;                 ws += (size_t)nChunks * 8 * 4;
  int* rowtok = (int*)ws;                    ws += (size_t)NEXP * capacity * 4;
  float* roww = (float*)ws;                  ws += (size_t)NEXP * capacity * 4;
  ws = (char*)(((uintptr_t)ws + 255) & ~(uintptr_t)255);
  size_t used = (size_t)(ws - (char*)d_ws);
  size_t avail = ws_size > used ? ws_size - used : 0;

  const size_t xbB  = (size_t)NEXP * capacity * HS * 2;   // 64 MB contiguous xb
  const size_t perE = ((size_t)FFN * HS * 2) * 2 + (size_t)capacity * FFN * 2; // w1t+w2t+h = 48 MB

  // Choose largest expert-group size G (with contiguous xb), else fallback path.
  int G = 0;
  for (int g = NEXP; g >= 1; g >>= 1)
    if (avail >= xbB + (size_t)g * perE) { G = g; break; }

  u16 *xb = nullptr, *xbf = nullptr, *w1t, *w2t, *h;
  if (G > 0) {
    xb  = (u16*)ws;  ws += xbB;
    w1t = (u16*)ws;  ws += (size_t)G * FFN * HS * 2;
    w2t = (u16*)ws;  ws += (size_t)G * HS * FFN * 2;
    h   = (u16*)ws;  ws += (size_t)G * capacity * FFN * 2;
  } else {
    // fallback (known-fits 81 MB): token-order bf16 x, gathered staging, G=1
    G = 1;
    xbf = (u16*)ws;  ws += (size_t)T * HS * 2;
    w1t = (u16*)ws;  ws += (size_t)FFN * HS * 2;
    w2t = (u16*)ws;  ws += (size_t)HS * FFN * 2;
    h   = (u16*)ws;  ws += (size_t)capacity * FFN * 2;
    if ((size_t)(ws - (char*)d_ws) > ws_size) return;
    convert_bf16<<<T * HS / 1024, 256, 0, stream>>>(x, xbf);
  }

  // router + stable binning + slot maps (+ contiguous gather if xb)
  router_kernel<<<T / 4, 256, 0, stream>>>(x, wr, T, experts, weights);
  hist_kernel<<<N / 256, 256, 0, stream>>>(experts, hist, lrank);
  scan_kernel<<<1, 512, 0, stream>>>(hist, chunkBase);
  slot_init<<<NEXP * capacity / 256, 256, 0, stream>>>(rowtok, roww);
  gather_kernel<<<N / 4, 256, 0, stream>>>(x, experts, lrank, chunkBase, weights,
                                           capacity, rowtok, roww, xb);
  // out = bias; GEMM2 scatter-adds on top
  bias_init<<<T, 256, 0, stream>>>(bias, out);

  for (int e0 = 0; e0 < NEXP; e0 += G) {
    const float* w1_g = w1 + (size_t)e0 * HS * FFN;
    const float* w2_g = w2 + (size_t)e0 * FFN * HS;
    const int* rt_g = rowtok + e0 * capacity;
    const float* rw_g = roww + e0 * capacity;
    transpose_convert<<<dim3(FFN / 32, HS / 32, G), 256, 0, stream>>>(w1_g, w1t, HS, FFN);
    transpose_convert<<<dim3(HS / 32, FFN / 32, G), 256, 0, stream>>>(w2_g, w2t, FFN, HS);
    if (xb != nullptr) {
      gemm_moe<true, false, false><<<dim3(FFN / 256, capacity / 256, G), 512, 0, stream>>>(
          xb + (size_t)e0 * capacity * HS, w1t, h, nullptr, rt_g, rw_g,
          capacity, capacity, FFN, HS);
    } else {
      gemm_moe<true, true, false><<<dim3(FFN / 256, capacity / 256, G), 512, 0, stream>>>(
          xbf, w1t, h, nullptr, rt_g, rw_g, capacity, capacity, FFN, HS);
    }
    gemm_moe<false, false, true><<<dim3(HS / 256, capacity / 256, G), 512, 0, stream>>>(
        h, w2t, nullptr, out, rt_g, rw_g, capacity, capacity, HS, FFN);
  }
}

// Round 2
// 1044.060 us; speedup vs baseline: 1.2520x; 1.0420x over previous
//
#include <hip/hip_runtime.h>
#include <stdint.h>
#include <math.h>

typedef unsigned short u16;
typedef __attribute__((ext_vector_type(8))) short bf16x8;   // 8 bf16 (4 VGPRs)
typedef __attribute__((ext_vector_type(4))) float f32x4;    // MFMA accumulator

#define HS   1024
#define NEXP 8
#define FFN  4096

// ---------- small helpers ----------
__device__ __forceinline__ u16 f2b(float f) {              // fp32 -> bf16, RNE
  uint32_t u = __builtin_bit_cast(uint32_t, f);
  u = (u + 0x7fffu + ((u >> 16) & 1u)) >> 16;
  return (u16)u;
}
__device__ __forceinline__ float gelu_tanh(float x) {      // JAX approximate=True
  float z = 0.7978845608028654f * (x + 0.044715f * x * x * x);
  float e = __expf(2.0f * z);
  return 0.5f * x * (1.0f + (1.0f - 2.0f / (e + 1.0f)));
}
__device__ __forceinline__ void gload_lds16(const void* g, void* l) {
  // async global->LDS, 16B/lane; global addr per-lane, LDS dst wave-uniform+lane*16
  __builtin_amdgcn_global_load_lds(
      (__attribute__((address_space(1))) void*)(void*)g,
      (__attribute__((address_space(3))) void*)l, 16, 0, 0);
}

// ---------- x: fp32 -> bf16, token order (fallback path only) ----------
__global__ __launch_bounds__(256) void convert_bf16(const float* __restrict__ in,
                                                    u16* __restrict__ out) {
  const int i = (blockIdx.x * 256 + threadIdx.x) * 4;
  float4 v = *(const float4*)(in + i);
  ushort4 o;
  o.x = f2b(v.x); o.y = f2b(v.y); o.z = f2b(v.z); o.w = f2b(v.w);
  *(ushort4*)(out + i) = o;
}

// ---------- transpose + convert (batched over z):  [z][K][N] f32 -> [z][N][K] bf16 ----------
__global__ __launch_bounds__(256) void transpose_convert(const float* __restrict__ in,
                                                         u16* __restrict__ out,
                                                         int K, int N) {
  __shared__ u16 tile[32][33];
  const int z = blockIdx.z;
  const int k0 = blockIdx.y * 32, n0 = blockIdx.x * 32;
  const int tx = threadIdx.x & 31, ty = threadIdx.x >> 5;   // 32 x 8
  const float* src = in + (size_t)z * K * N;
  u16* dst = out + (size_t)z * N * K;
#pragma unroll
  for (int i = 0; i < 4; ++i)
    tile[ty + i * 8][tx] = f2b(src[(size_t)(k0 + ty + i * 8) * N + n0 + tx]);
  __syncthreads();
#pragma unroll
  for (int i = 0; i < 4; ++i)
    dst[(size_t)(n0 + ty + i * 8) * K + k0 + tx] = tile[tx][ty + i * 8];
}

// ---------- router: fp64 logits, softmax, top-2 (tie -> lower index) ----------
__global__ __launch_bounds__(256) void router_kernel(const float* __restrict__ x,
                                                     const float* __restrict__ wr,
                                                     int T, int* __restrict__ experts,
                                                     float* __restrict__ weights) {
  const int wave = threadIdx.x >> 6, lane = threadIdx.x & 63;
  const int t = blockIdx.x * 4 + wave;
  if (t >= T) return;
  const float* xr = x + (size_t)t * HS;
  double acc[8] = {0, 0, 0, 0, 0, 0, 0, 0};
#pragma unroll
  for (int i = 0; i < HS / 64; ++i) {
    const int hrow = i * 64 + lane;
    double xv = (double)xr[hrow];
    float4 w0 = *(const float4*)(wr + hrow * 8);
    float4 w1 = *(const float4*)(wr + hrow * 8 + 4);
    acc[0] += xv * (double)w0.x; acc[1] += xv * (double)w0.y;
    acc[2] += xv * (double)w0.z; acc[3] += xv * (double)w0.w;
    acc[4] += xv * (double)w1.x; acc[5] += xv * (double)w1.y;
    acc[6] += xv * (double)w1.z; acc[7] += xv * (double)w1.w;
  }
#pragma unroll
  for (int e = 0; e < 8; ++e) {
    double v = acc[e];
#pragma unroll
    for (int off = 32; off > 0; off >>= 1) v += __shfl_xor(v, off, 64);
    acc[e] = v;
  }
  if (lane == 0) {
    double m = acc[0];
#pragma unroll
    for (int e = 1; e < 8; ++e) m = acc[e] > m ? acc[e] : m;
    double s[8], sum = 0.0;
#pragma unroll
    for (int e = 0; e < 8; ++e) { s[e] = exp(acc[e] - m); sum += s[e]; }
    double inv = 1.0 / sum;
    int e1 = 0; double l1 = acc[0];
#pragma unroll
    for (int e = 1; e < 8; ++e) if (acc[e] > l1) { l1 = acc[e]; e1 = e; }
    int e2 = -1; double l2 = -1e300;
#pragma unroll
    for (int e = 0; e < 8; ++e) if (e != e1 && acc[e] > l2) { l2 = acc[e]; e2 = e; }
    experts[2 * t] = e1;  experts[2 * t + 1] = e2;
    weights[2 * t] = (float)(s[e1] * inv);
    weights[2 * t + 1] = (float)(s[e2] * inv);
  }
}

// ---------- per-wave expert histogram + in-wave stable rank ----------
__global__ __launch_bounds__(256) void hist_kernel(const int* __restrict__ experts,
                                                   int* __restrict__ hist,
                                                   unsigned char* __restrict__ lrank) {
  const int n = blockIdx.x * 256 + threadIdx.x;
  const int lane = threadIdx.x & 63;
  const int wid = n >> 6;
  const int e = experts[n];
  int rank = 0;
#pragma unroll
  for (int ev = 0; ev < 8; ++ev) {
    unsigned long long m = __ballot(e == ev);
    if (lane == ev) hist[wid * 8 + ev] = __popcll(m);
    if (e == ev) rank = __popcll(m & ((1ull << lane) - 1ull));
  }
  lrank[n] = (unsigned char)rank;
}

// ---------- single-block scan: chunk-EXCLUSIVE prefix per expert ----------
__global__ __launch_bounds__(512) void scan_kernel(const int* __restrict__ hist,
                                                   int* __restrict__ chunkBase) {
  __shared__ int s[512];
  const int tid = threadIdx.x;     // 512 == nChunks
  for (int e = 0; e < 8; ++e) {
    int v = hist[tid * 8 + e];
    s[tid] = v;
    __syncthreads();
    for (int off = 1; off < 512; off <<= 1) {
      int add = (tid >= off) ? s[tid - off] : 0;
      __syncthreads();
      s[tid] += add;
      __syncthreads();
    }
    chunkBase[tid * 8 + e] = s[tid] - v;   // exclusive, within-expert offset
    __syncthreads();
  }
}

// ---------- slot map init ----------
__global__ __launch_bounds__(256) void slot_init(int* __restrict__ rowtok,
                                                 float* __restrict__ roww) {
  const int i = blockIdx.x * 256 + threadIdx.x;
  rowtok[i] = -1;
  roww[i] = 0.0f;
}

// ---------- gather: fill rowtok/roww; optionally write xb[slot] = bf16(x[token]) ----------
__global__ __launch_bounds__(256) void gather_kernel(const float* __restrict__ x,
                                                     const int* __restrict__ experts,
                                                     const unsigned char* __restrict__ lrank,
                                                     const int* __restrict__ chunkBase,
                                                     const float* __restrict__ weights,
                                                     int capacity, int* __restrict__ rowtok,
                                                     float* __restrict__ roww,
                                                     u16* __restrict__ xb) {
  const int wave = threadIdx.x >> 6, lane = threadIdx.x & 63;
  const int n = blockIdx.x * 4 + wave;           // one wave per assignment
  const int e = experts[n];
  const int off = chunkBase[(n >> 6) * 8 + e] + (int)lrank[n];
  if (off >= capacity) return;
  const int slot = e * capacity + off;
  if (lane == 0) { rowtok[slot] = n >> 1; roww[slot] = weights[n]; }
  if (xb == nullptr) return;
  const float* src = x + (size_t)(n >> 1) * HS;
  u16* dst = xb + (size_t)slot * HS;
#pragma unroll
  for (int i = 0; i < 4; ++i) {
    float4 v = *(const float4*)(src + i * 256 + lane * 4);
    ushort4 o;
    o.x = f2b(v.x); o.y = f2b(v.y); o.z = f2b(v.z); o.w = f2b(v.w);
    *(ushort4*)(dst + i * 256 + lane * 4) = o;
  }
}

// ---------- bias broadcast into out ----------
__global__ __launch_bounds__(256) void bias_init(const float* __restrict__ bias,
                                                 float* __restrict__ out) {
  const int c = threadIdx.x * 4;
  *(float4*)(out + (size_t)blockIdx.x * HS + c) = *(const float4*)(bias + c);
}

// ============================================================================
// 256x256 / BK=64 / 8-wave / 8-phase GEMM.  Changes vs prev round:
//  * ONE barrier per phase (before MFMA).  Trailing barriers kept ONLY after
//    the vmcnt(4) tails at p3/p7 (cross-wave staged-data-visibility).  Hazard
//    proof: with barrier skew <= 1 segment, every LDS region's ds_reads are
//    register-consumed (lgkm before that wave's MFMA -> before it reaches the
//    next barrier) >= 1 barrier before any wave can issue the stage that
//    overwrites it (B1@S0 vs M7', A0@S2 vs M0, B0@S4 vs M3, A1@S6 vs M4).
//    This lets waves desync so LDS reads overlap the MFMA pipe.
//  * T1 bijective XCD-chunked blockIdx remap + 4-wide bn supertiles (both
//    grids are %8==0): one expert per XCD, squarish resident panel set.
// Staging schedule per iter (tiles T0=2I buf0 / T1=2I+1 buf1):
//   p0:S_B(T1)h0  p1:S_B(T1)h1  p2:S_A(T0+2)h0  p3:S_A(T0+2)h1, vmcnt(4), BAR
//   p4:S_B(T0+2)h0 p5:S_B(T0+2)h1 p6:S_A(T1+2)h0 p7:S_A(T1+2)h1, vmcnt(4), BAR
// vmcnt(4)@p3 completes {A(T1),B(T1)}; @p7 completes {A(T0+2),B(T0+2)}.
// LDS swizzle: byte b holds element (b ^ ((row&7)<<4)) — inverse-swizzled
// global SOURCE + linear gload_lds dest + swizzled ds_read (rule #21).
// ============================================================================
#define VMCNT(n) asm volatile("s_waitcnt vmcnt(" #n ")" ::: "memory")
#define BAR() do { asm volatile("" ::: "memory"); \
                   __builtin_amdgcn_s_barrier();  \
                   asm volatile("" ::: "memory"); } while (0)

template <bool GELU, bool GATHER_A, bool SCATTER>
__global__ __launch_bounds__(512, 2) void gemm_moe(const u16* __restrict__ A,
                                                   const u16* __restrict__ Bt,
                                                   u16* __restrict__ Cout,
                                                   float* __restrict__ out,
                                                   const int* __restrict__ rowtok,
                                                   const float* __restrict__ roww,
                                                   int rtStride, int M, int Nn, int K) {
  // ---- T1: XCD-chunked bijective remap + bn-supertiles (perf-only) ----
  int bn, bm, z;
  {
    const int gx = gridDim.x, gy = gridDim.y, gz = gridDim.z;
    const int nwg = gx * gy * gz;
    const int flat = (blockIdx.z * gy + blockIdx.y) * gx + blockIdx.x;
    const int q = nwg >> 3, r = nwg & 7;
    const int xcd = flat & 7, idx = flat >> 3;
    const int base = (xcd < r) ? xcd * (q + 1) : r * (q + 1) + (xcd - r) * q;
    int nid = base + idx;
    const int perz = gx * gy;
    z = nid / perz;
    int rem = nid - z * perz;
    const int GN = (gx >= 4) ? 4 : gx;          // bn-group width
    const int grpsz = GN * gy;
    const int grp = rem / grpsz, ir = rem - grp * grpsz;
    const int bnl = ir % GN;
    bm = ir / GN;
    bn = grp * GN + bnl;
  }

  if (!GATHER_A) A += (size_t)z * M * K;
  Bt += (size_t)z * Nn * K;
  rowtok += (size_t)z * rtStride;
  roww += (size_t)z * rtStride;
  const u16* Bb = Bt + (size_t)bn * 256 * K;

  __shared__ u16 lds[65536];          // 128 KiB: A0 A1 B0 B1, 32 KiB each
  char* ldsA = (char*)lds;
  char* ldsB = ldsA + 65536;

  const int tid = threadIdx.x;
  const int lane = tid & 63;
  const int lrow = lane & 15, quad = lane >> 4;
  const int wid = tid >> 6, wm = wid >> 2, wn = wid & 3;  // 2x4 waves -> 128x64 each

  // swizzled read offsets: byte = row*128 + ((ks*64 + quad*16) ^ ((row&7)<<4))
  const int swz = (lane & 7) << 4;                        // row&7 == lane&7
  const int kq0 = (quad * 16) ^ swz;
  const int kq1 = (64 + quad * 16) ^ swz;
  const int aBase = (wm * 128 + lrow) * 128;
  const int bBase = (wn * 64 + lrow) * 128;

  // staging sources: 4 row-steps of 64 rows; source col inverse-swizzled
  const u16 *gA[4], *gB[4];
#pragma unroll
  for (int s = 0; s < 4; ++s) {
    const int srow = s * 64 + (tid >> 3);
    const int scol = ((tid & 7) * 8) ^ ((srow & 7) << 3);   // elements
    if (GATHER_A) {
      int t = rowtok[bm * 256 + srow]; if (t < 0) t = 0;
      gA[s] = A + (size_t)t * K + scol;
    } else {
      gA[s] = A + (size_t)(bm * 256 + srow) * K + scol;
    }
    gB[s] = Bb + (size_t)srow * K + scol;
  }
  const int ldst0 = tid * 16;   // linear byte within step (gload dest)

#define STAGE_A(buf, half, kt) do { \
    gload_lds16(gA[(half)*2]   + (size_t)(kt) * 64, ldsA + (buf)*32768 + (half)*16384 +        ldst0); \
    gload_lds16(gA[(half)*2+1] + (size_t)(kt) * 64, ldsA + (buf)*32768 + (half)*16384 + 8192 + ldst0); \
  } while (0)
#define STAGE_B(buf, half, kt) do { \
    gload_lds16(gB[(half)*2]   + (size_t)(kt) * 64, ldsB + (buf)*32768 + (half)*16384 +        ldst0); \
    gload_lds16(gB[(half)*2+1] + (size_t)(kt) * 64, ldsB + (buf)*32768 + (half)*16384 + 8192 + ldst0); \
  } while (0)

  f32x4 acc[8][4] = {};
  bf16x8 a[8][2];

#define LOAD_A(ABUF) \
  _Pragma("unroll") \
  for (int m = 0; m < 8; ++m) { \
    a[m][0] = *(const bf16x8*)((ABUF) + aBase + m * 2048 + kq0); \
    a[m][1] = *(const bf16x8*)((ABUF) + aBase + m * 2048 + kq1); \
  }

// One barrier per phase (before MFMA); END_STMT only at group boundaries.
#define PHASE(BBUF, NF, STAGE_STMT, END_STMT) do { \
    bf16x8 pb0 = *(const bf16x8*)((BBUF) + bBase + (NF) * 2048 + kq0); \
    bf16x8 pb1 = *(const bf16x8*)((BBUF) + bBase + (NF) * 2048 + kq1); \
    STAGE_STMT; \
    BAR(); \
    __builtin_amdgcn_s_setprio(1); \
    _Pragma("unroll") \
    for (int m = 0; m < 8; ++m) { \
      acc[m][NF] = __builtin_amdgcn_mfma_f32_16x16x32_bf16(a[m][0], pb0, acc[m][NF], 0, 0, 0); \
      acc[m][NF] = __builtin_amdgcn_mfma_f32_16x16x32_bf16(a[m][1], pb1, acc[m][NF], 0, 0, 0); \
    } \
    __builtin_amdgcn_s_setprio(0); \
    END_STMT; \
  } while (0)

  // prologue: A(0)->A0, B(0)->B0, A(1)->A1 ; wait A(0),B(0) (A(1) stays in flight)
  STAGE_A(0, 0, 0); STAGE_A(0, 1, 0);
  STAGE_B(0, 0, 0); STAGE_B(0, 1, 0);
  STAGE_A(1, 0, 1); STAGE_A(1, 1, 1);
  VMCNT(4);
  BAR();

  const int nIter = K >> 7;            // K/128, >=1; K multiple of 128
  for (int I = 0; I < nIter; ++I) {
    const int T1 = 2 * I + 1;
    const bool hn = (I + 1 < nIter);
    // ---- tile 2I from buf0 ----
    LOAD_A(ldsA);
    PHASE(ldsB, 0, STAGE_B(1, 0, T1), ((void)0));
    PHASE(ldsB, 1, STAGE_B(1, 1, T1), ((void)0));
    PHASE(ldsB, 2, do { if (hn) STAGE_A(0, 0, T1 + 1); } while (0), ((void)0));
    PHASE(ldsB, 3, do { if (hn) STAGE_A(0, 1, T1 + 1); } while (0),
          do { if (hn) { VMCNT(4); } else { VMCNT(0); } BAR(); } while (0));
    // ---- tile 2I+1 from buf1 ----
    LOAD_A(ldsA + 32768);
    PHASE(ldsB + 32768, 0, do { if (hn) STAGE_B(0, 0, T1 + 1); } while (0), ((void)0));
    PHASE(ldsB + 32768, 1, do { if (hn) STAGE_B(0, 1, T1 + 1); } while (0), ((void)0));
    PHASE(ldsB + 32768, 2, do { if (hn) STAGE_A(1, 0, T1 + 2); } while (0), ((void)0));
    PHASE(ldsB + 32768, 3, do { if (hn) STAGE_A(1, 1, T1 + 2); } while (0),
          do { if (hn) { VMCNT(4); } BAR(); } while (0));
  }

  // epilogue — C/D layout: col=lane&15, row=quad*4+reg (m89-verified)
  const int rbase = bm * 256 + wm * 128 + quad * 4;
  const int cbase = bn * 256 + wn * 64 + lrow;
  if (!SCATTER) {
    u16* Cb = Cout + (size_t)z * M * Nn;
#pragma unroll
    for (int m = 0; m < 8; ++m)
#pragma unroll
      for (int nf = 0; nf < 4; ++nf)
#pragma unroll
        for (int r = 0; r < 4; ++r) {
          float v = acc[m][nf][r];
          if (GELU) v = gelu_tanh(v);
          Cb[(size_t)(rbase + m * 16 + r) * Nn + cbase + nf * 16] = f2b(v);
        }
  } else {
#pragma unroll
    for (int m = 0; m < 8; ++m)
#pragma unroll
      for (int r = 0; r < 4; ++r) {
        const int row = rbase + m * 16 + r;
        const int tok = rowtok[row];
        if (tok >= 0) {
          const float w = roww[row];
          float* op = out + (size_t)tok * HS + cbase;
#pragma unroll
          for (int nf = 0; nf < 4; ++nf)
            atomicAdd(op + nf * 16, w * acc[m][nf][r]);
        }
      }
  }
}

extern "C" void kernel_launch(void* const* d_in, const int* in_sizes, int n_in,
                              void* d_out, int out_size, void* d_ws, size_t ws_size,
                              hipStream_t stream) {
  const float* x    = (const float*)d_in[0];
  const float* wr   = (const float*)d_in[1];
  const float* w1   = (const float*)d_in[2];
  const float* w2   = (const float*)d_in[3];
  const float* bias = (const float*)d_in[4];
  float* out = (float*)d_out;

  const int T = in_sizes[0] / HS;          // 16384
  const int N = T * 2;                     // 32768 assignments
  const int capacity = N / NEXP;           // 4096
  const int nChunks = N / 64;              // 512

  // ---- small workspace ----
  char* ws = (char*)d_ws;
  int* experts = (int*)ws;                   ws += (size_t)N * 4;
  float* weights = (float*)ws;               ws += (size_t)N * 4;
  unsigned char* lrank = (unsigned char*)ws; ws += (size_t)N;
  int* hist = (int*)ws;                      ws += (size_t)nChunks * 8 * 4;
  int* chunkBase = (int*)ws;                 ws += (size_t)nChunks * 8 * 4;
  int* rowtok = (int*)ws;                    ws += (size_t)NEXP * capacity * 4;
  float* roww = (float*)ws;                  ws += (size_t)NEXP * capacity * 4;
  ws = (char*)(((uintptr_t)ws + 255) & ~(uintptr_t)255);
  size_t used = (size_t)(ws - (char*)d_ws);
  size_t avail = ws_size > used ? ws_size - used : 0;

  const size_t xbB  = (size_t)NEXP * capacity * HS * 2;   // 64 MB contiguous xb
  const size_t perE = ((size_t)FFN * HS * 2) * 2 + (size_t)capacity * FFN * 2; // w1t+w2t+h = 48 MB

  // Choose largest expert-group size G (with contiguous xb), else fallback path.
  int G = 0;
  for (int g = NEXP; g >= 1; g >>= 1)
    if (avail >= xbB + (size_t)g * perE) { G = g; break; }

  u16 *xb = nullptr, *xbf = nullptr, *w1t, *w2t, *h;
  if (G > 0) {
    xb  = (u16*)ws;  ws += xbB;
    w1t = (u16*)ws;  ws += (size_t)G * FFN * HS * 2;
    w2t = (u16*)ws;  ws += (size_t)G * HS * FFN * 2;
    h   = (u16*)ws;  ws += (size_t)G * capacity * FFN * 2;
  } else {
    // fallback (known-fits 81 MB): token-order bf16 x, gathered staging, G=1
    G = 1;
    xbf = (u16*)ws;  ws += (size_t)T * HS * 2;
    w1t = (u16*)ws;  ws += (size_t)FFN * HS * 2;
    w2t = (u16*)ws;  ws += (size_t)HS * FFN * 2;
    h   = (u16*)ws;  ws += (size_t)capacity * FFN * 2;
    if ((size_t)(ws - (char*)d_ws) > ws_size) return;
    convert_bf16<<<T * HS / 1024, 256, 0, stream>>>(x, xbf);
  }

  // router + stable binning + slot maps (+ contiguous gather if xb)
  router_kernel<<<T / 4, 256, 0, stream>>>(x, wr, T, experts, weights);
  hist_kernel<<<N / 256, 256, 0, stream>>>(experts, hist, lrank);
  scan_kernel<<<1, 512, 0, stream>>>(hist, chunkBase);
  slot_init<<<NEXP * capacity / 256, 256, 0, stream>>>(rowtok, roww);
  gather_kernel<<<N / 4, 256, 0, stream>>>(x, experts, lrank, chunkBase, weights,
                                           capacity, rowtok, roww, xb);
  // out = bias; GEMM2 scatter-adds on top
  bias_init<<<T, 256, 0, stream>>>(bias, out);

  for (int e0 = 0; e0 < NEXP; e0 += G) {
    const float* w1_g = w1 + (size_t)e0 * HS * FFN;
    const float* w2_g = w2 + (size_t)e0 * FFN * HS;
    const int* rt_g = rowtok + e0 * capacity;
    const float* rw_g = roww + e0 * capacity;
    transpose_convert<<<dim3(FFN / 32, HS / 32, G), 256, 0, stream>>>(w1_g, w1t, HS, FFN);
    transpose_convert<<<dim3(HS / 32, FFN / 32, G), 256, 0, stream>>>(w2_g, w2t, FFN, HS);
    if (xb != nullptr) {
      gemm_moe<true, false, false><<<dim3(FFN / 256, capacity / 256, G), 512, 0, stream>>>(
          xb + (size_t)e0 * capacity * HS, w1t, h, nullptr, rt_g, rw_g,
          capacity, capacity, FFN, HS);
    } else {
      gemm_moe<true, true, false><<<dim3(FFN / 256, capacity / 256, G), 512, 0, stream>>>(
          xbf, w1t, h, nullptr, rt_g, rw_g, capacity, capacity, FFN, HS);
    }
    gemm_moe<false, false, true><<<dim3(HS / 256, capacity / 256, G), 512, 0, stream>>>(
        h, w2t, nullptr, out, rt_g, rw_g, capacity, capacity, HS, FFN);
  }
}